// Round 4
// baseline (525.430 us; speedup 1.0000x reference)
//
#include <hip/hip_runtime.h>

#define NTOK 32768   // 8*64*64 tokens
#define CIN 192
#define C3 576
#define HEADS 8
#define HD 24

typedef __attribute__((ext_vector_type(8))) short bf16x8;
typedef __attribute__((ext_vector_type(16))) float f32x16;

__device__ __forceinline__ float bf2f(unsigned int u) {
  union { unsigned int i; float f; } x; x.i = u << 16; return x.f;
}
__device__ __forceinline__ unsigned short f2bf(float f) {
  union { float f; unsigned int i; } x; x.f = f;
  unsigned int r = x.i + 0x7fffu + ((x.i >> 16) & 1u);
  return (unsigned short)(r >> 16);
}

// ---------------------------------------------------------------------------
// MFMA GEMM: Y[o,n] = bias[o] + sum_{c<192} W[o,c] * X[c,n]
// block 256 = 4 waves; tile 64(o) x 64(n); full K=192 staged once.
// 1D grid, XCD-chunked swizzle (o fastest within an XCD's n-range).
// ---------------------------------------------------------------------------
template<int XBF, int OUTF32>
__global__ __launch_bounds__(256) void k_gemm_mfma(
    const void* __restrict__ Xv, const float* __restrict__ W,
    const float* __restrict__ bias, void* __restrict__ Yv, int ot)
{
  __shared__ __align__(16) unsigned short Wl[64][200];
  __shared__ __align__(16) unsigned short Xs[64][200];
  const int tid = threadIdx.x;
  const int bid = blockIdx.x;
  const int loc = bid >> 3;
  const int n0 = ((bid & 7) * 64 + loc / ot) * 64;
  const int o0 = (loc % ot) * 64;

  { // stage W (fp32 -> bf16)
    const int oo = tid >> 2;
    const int q0 = tid & 3;
#pragma unroll
    for (int j = 0; j < 12; ++j) {
      const int c = (j * 4 + q0) * 4;
      float4 v = *(const float4*)&W[(size_t)(o0 + oo) * CIN + c];
      Wl[oo][c]     = f2bf(v.x);
      Wl[oo][c + 1] = f2bf(v.y);
      Wl[oo][c + 2] = f2bf(v.z);
      Wl[oo][c + 3] = f2bf(v.w);
    }
  }
  { // stage X transposed -> Xs[n][c]
    const int nn = (tid & 31) * 2;
    const int cg = tid >> 5;
    if (XBF) {
      const unsigned short* X = (const unsigned short*)Xv;
#pragma unroll
      for (int j = 0; j < 24; ++j) {
        const int c = j * 8 + cg;
        unsigned int w = *(const unsigned int*)&X[(size_t)c * NTOK + n0 + nn];
        Xs[nn][c]     = (unsigned short)(w & 0xffffu);
        Xs[nn + 1][c] = (unsigned short)(w >> 16);
      }
    } else {
      const float* X = (const float*)Xv;
#pragma unroll
      for (int j = 0; j < 24; ++j) {
        const int c = j * 8 + cg;
        float2 v = *(const float2*)&X[(size_t)c * NTOK + n0 + nn];
        Xs[nn][c]     = f2bf(v.x);
        Xs[nn + 1][c] = f2bf(v.y);
      }
    }
  }
  __syncthreads();

  const int lane = tid & 63;
  const int wv = tid >> 6;
  const int o_w = (wv >> 1) * 32;
  const int n_w = (wv & 1) * 32;
  const int r32 = lane & 31;
  const int hi = lane >> 5;

  f32x16 acc;
#pragma unroll
  for (int i = 0; i < 16; ++i) acc[i] = 0.f;

  const unsigned short* wp = &Wl[o_w + r32][hi * 8];
  const unsigned short* xp = &Xs[n_w + r32][hi * 8];
#pragma unroll
  for (int kk = 0; kk < 12; ++kk) {
    bf16x8 a = *(const bf16x8*)(wp + kk * 16);
    bf16x8 b = *(const bf16x8*)(xp + kk * 16);
    acc = __builtin_amdgcn_mfma_f32_32x32x16_bf16(a, b, acc, 0, 0, 0);
  }
  __syncthreads();

  if (OUTF32) {
    float (*Yl)[68] = (float(*)[68])&Wl[0][0];
#pragma unroll
    for (int r = 0; r < 16; ++r) {
      const int row = o_w + (r & 3) + 8 * (r >> 2) + 4 * hi;
      Yl[row][n_w + r32] = acc[r] + bias[o0 + row];
    }
    __syncthreads();
    float* Y = (float*)Yv;
    const int row = tid >> 2, seg = (tid & 3) * 16;
#pragma unroll
    for (int v = 0; v < 4; ++v) {
      float4 val = *(const float4*)&Yl[row][seg + v * 4];
      *(float4*)&Y[(size_t)(o0 + row) * NTOK + n0 + seg + v * 4] = val;
    }
  } else {
    unsigned short (*Yl)[72] = (unsigned short(*)[72])&Wl[0][0];
#pragma unroll
    for (int r = 0; r < 16; ++r) {
      const int row = o_w + (r & 3) + 8 * (r >> 2) + 4 * hi;
      Yl[row][n_w + r32] = f2bf(acc[r] + bias[o0 + row]);
    }
    __syncthreads();
    unsigned short* Y = (unsigned short*)Yv;
    const int row = tid >> 2, seg = (tid & 3) * 16;
#pragma unroll
    for (int v = 0; v < 2; ++v) {
      bf16x8 val = *(const bf16x8*)&Yl[row][seg + v * 8];
      *(bf16x8*)&Y[(size_t)(o0 + row) * NTOK + n0 + seg + v * 8] = val;
    }
  }
}

// ---------------------------------------------------------------------------
// A-fragment table for banded-MFMA depthwise conv.
// atab[c][f = dt*9+dw*3+s][lane][e] (bf16), 576*27*64*8 elems.
// A[i][k] for 32x32x16 mfma: i = lane&31, k = (lane>>5)*8+e.
// slab s: h_lds base offset {0,16,24}; dh = k - i + {0,16,24}; s=2 needs k>=8.
// ---------------------------------------------------------------------------
__global__ __launch_bounds__(64) void k_build_atab(
    const float* __restrict__ wdw, unsigned short* __restrict__ atab)
{
  const int c = blockIdx.x;
  const int lane = threadIdx.x;
  const int i = lane & 31;
  const int kg = lane >> 5;
  float K[27];
#pragma unroll
  for (int q = 0; q < 27; ++q) K[q] = wdw[c * 27 + q];
#pragma unroll
  for (int dt = 0; dt < 3; ++dt)
#pragma unroll
    for (int dw = 0; dw < 3; ++dw)
#pragma unroll
      for (int s = 0; s < 3; ++s) {
        bf16x8 pk;
#pragma unroll
        for (int e = 0; e < 8; ++e) {
          const int k = kg * 8 + e;
          int dh; bool use;
          if (s == 0)      { dh = k - i;      use = (dh >= 0 && dh <= 2); }
          else if (s == 1) { dh = k + 16 - i; use = (dh >= 0 && dh <= 2); }
          else             { dh = k + 24 - i; use = (dh >= 0 && dh <= 2) && (k >= 8); }
          unsigned short v = 0;
          if (use) v = f2bf(K[dt * 9 + dh * 3 + dw]);
          pk[e] = (short)v;
        }
        size_t off = ((size_t)(c * 27 + dt * 9 + dw * 3 + s) * 64 + lane) * 8;
        *(bf16x8*)&atab[off] = pk;
      }
}

// ---------------------------------------------------------------------------
// K2: depthwise 3x3x3 via banded MFMA.
// block = (wblk in {0,1}, channel); 256 thr = 4 waves = (H in {0,1}, tq in {0,1}).
// LDS: transposed padded input S[t 8][w_lds 34][h_lds 72] bf16 (39.2 KB).
//   w_lds = w - (wblk*32 - 1) (covers w-halo), h_lds = h + 1 (zero rows 0, 65..71).
// Per (t, dt): 9 A-frags from atab (global, L2-hot), 9 B ds_read_b128, 9 MFMA.
// ---------------------------------------------------------------------------
__global__ __launch_bounds__(256) void k_dwconv_mfma(
    const unsigned short* __restrict__ in,   // [CH_chunk][8][64][64] bf16
    const unsigned short* __restrict__ atab, // [576][27][64][8] bf16
    const float* __restrict__ bdw,           // [576]
    unsigned short* __restrict__ out,        // [576][8][64][64] bf16
    int c_start)
{
  __shared__ __align__(16) unsigned short S[8][34][72];
  const int tid = threadIdx.x;
  const int wblk = blockIdx.x;
  const int chl = blockIdx.y;
  const int ch = c_start + chl;
  const unsigned short* inch = in + (size_t)chl * NTOK;

  // ---- zero pad rows: h_lds 0 and 65..71 for all (t, w_lds)
  for (int idx = tid; idx < 8 * 34 * 8; idx += 256) {
    const int t = idx / 272;
    const int rem = idx % 272;
    const int wl = rem >> 3;
    const int z = rem & 7;
    const int hl = (z == 0) ? 0 : 64 + z;
    S[t][wl][hl] = 0;
  }
  // ---- stage: rows r = (t,h), each 34 shorts from w = wblk*32-1 .. +32
  {
    const int wg0 = wblk * 32 - 2;  // u32-aligned first w
#pragma unroll
    for (int rr = 0; rr < 2; ++rr) {
      const int r = tid * 2 + rr;
      const int t = r >> 6, h = r & 63;
      const unsigned short* rowp = inch + t * 4096 + h * 64;
#pragma unroll
      for (int u = 0; u < 18; ++u) {
        const int w = wg0 + 2 * u;
        unsigned int pv = 0;
        if (w >= 0 && w <= 62) pv = *(const unsigned int*)&rowp[w];
        const int wl0 = 2 * u - 1;
        if (wl0 >= 0)  S[t][wl0][h + 1]     = (unsigned short)(pv & 0xffffu);
        if (wl0 < 33)  S[t][wl0 + 1][h + 1] = (unsigned short)(pv >> 16);
      }
    }
  }
  __syncthreads();

  const int lane = tid & 63;
  const int wv = tid >> 6;
  const int H = wv & 1;
  const int tq = wv >> 1;
  const int j32 = lane & 31;
  const int kg = lane >> 5;
  const float bias = bdw[ch];
  const unsigned short* atc = atab + (size_t)ch * (27 * 512) + (size_t)lane * 8;

  for (int t = tq * 4; t < tq * 4 + 4; ++t) {
    f32x16 acc;
#pragma unroll
    for (int i = 0; i < 16; ++i) acc[i] = 0.f;

#pragma unroll
    for (int dt = 0; dt < 3; ++dt) {
      const int tin = t + dt - 1;
      if (tin < 0 || tin > 7) continue;
      bf16x8 A[9];
#pragma unroll
      for (int f = 0; f < 9; ++f)
        A[f] = *(const bf16x8*)(atc + (size_t)(dt * 9 + f) * 512);
#pragma unroll
      for (int dw = 0; dw < 3; ++dw) {
        const unsigned short* bp = &S[tin][j32 + dw][0];
#pragma unroll
        for (int s = 0; s < 3; ++s) {
          const int sb = (s == 0) ? 0 : (s == 1 ? 16 : 24);
          bf16x8 b = *(const bf16x8*)(bp + 32 * H + sb + kg * 8);
          acc = __builtin_amdgcn_mfma_f32_32x32x16_bf16(A[dw * 3 + s], b, acc, 0, 0, 0);
        }
      }
    }
    unsigned short* outp = out + (size_t)ch * NTOK + t * 4096 + wblk * 32 + j32;
#pragma unroll
    for (int r = 0; r < 16; ++r) {
      const int hrow = 32 * H + (r & 3) + 8 * (r >> 2) + 4 * kg;
      outp[hrow * 64] = f2bf(acc[r] + bias);
    }
  }
}

// ---------------------------------------------------------------------------
// K3: Gram S[c,d] = sum_n q[c,n]k[d,n] + row sumsq, per head (bf16 input).
// ---------------------------------------------------------------------------
__global__ __launch_bounds__(256) void k_gram(
    const unsigned short* __restrict__ post,
    float* __restrict__ Sb, float* __restrict__ nqb, float* __restrict__ nkb)
{
  const int tid = threadIdx.x;
  const int h = blockIdx.y;
  const int n0 = blockIdx.x * 1024;
  const unsigned short* q = post + (size_t)(h * HD) * NTOK;
  const unsigned short* k = post + (size_t)(192 + h * HD) * NTOK;
  __shared__ float qs[32][65];
  __shared__ float ks[32][65];

  for (int i = tid; i < 8 * 64; i += 256) {
    int r = 24 + (i >> 6);
    qs[r][i & 63] = 0.f;
    ks[r][i & 63] = 0.f;
  }

  const int ty = tid >> 4;
  const int tx = tid & 15;
  float a00 = 0, a01 = 0, a10 = 0, a11 = 0;
  float sq = 0;

  for (int sub = 0; sub < 16; ++sub) {
    __syncthreads();
    for (int i = tid; i < 768; i += 256) {
      int r = i >> 5, cc = (i & 31) * 2;
      int col = n0 + (sub << 6) + cc;
      unsigned int wq = *(const unsigned int*)&q[(size_t)r * NTOK + col];
      unsigned int wk = *(const unsigned int*)&k[(size_t)r * NTOK + col];
      qs[r][cc] = bf2f(wq & 0xffffu); qs[r][cc + 1] = bf2f(wq >> 16);
      ks[r][cc] = bf2f(wk & 0xffffu); ks[r][cc + 1] = bf2f(wk >> 16);
    }
    __syncthreads();
#pragma unroll 8
    for (int j = 0; j < 64; ++j) {
      float q0 = qs[ty * 2][j], q1 = qs[ty * 2 + 1][j];
      float k0 = ks[tx * 2][j], k1 = ks[tx * 2 + 1][j];
      a00 += q0 * k0; a01 += q0 * k1; a10 += q1 * k0; a11 += q1 * k1;
    }
    if (tid < 24) {
#pragma unroll 8
      for (int j = 0; j < 64; ++j) { float v = qs[tid][j]; sq += v * v; }
    } else if (tid < 48) {
#pragma unroll 8
      for (int j = 0; j < 64; ++j) { float v = ks[tid - 24][j]; sq += v * v; }
    }
  }
  const int c0 = ty * 2, d0 = tx * 2;
  if (c0 < 24 && d0 < 24) {
    atomicAdd(&Sb[h * 576 + c0 * 24 + d0], a00);
    atomicAdd(&Sb[h * 576 + c0 * 24 + d0 + 1], a01);
    atomicAdd(&Sb[h * 576 + (c0 + 1) * 24 + d0], a10);
    atomicAdd(&Sb[h * 576 + (c0 + 1) * 24 + d0 + 1], a11);
  }
  if (tid < 24) atomicAdd(&nqb[h * 24 + tid], sq);
  else if (tid < 48) atomicAdd(&nkb[h * 24 + tid - 24], sq);
}

// ---------------------------------------------------------------------------
// K4: attn = softmax(S*temp/(|q||k|)); Wcomb = projW @ attn (per head)
// ---------------------------------------------------------------------------
__global__ __launch_bounds__(256) void k_attn_wcomb(
    const float* __restrict__ Sb, const float* __restrict__ nqb,
    const float* __restrict__ nkb, const float* __restrict__ temp,
    const float* __restrict__ projw, float* __restrict__ wcomb)
{
  const int h = blockIdx.x;
  const int tid = threadIdx.x;
  __shared__ float attn[24][25];
  __shared__ float nqs[24], nks[24];
  if (tid < 24) nqs[tid] = fmaxf(sqrtf(nqb[h * 24 + tid]), 1e-12f);
  else if (tid < 48) nks[tid - 24] = fmaxf(sqrtf(nkb[h * 24 + tid - 24]), 1e-12f);
  __syncthreads();
  if (tid < 24) {
    const int c = tid;
    const float tmp = temp[h];
    float row[24];
    float m = -1e30f;
#pragma unroll
    for (int d = 0; d < 24; ++d) {
      float v = Sb[h * 576 + c * 24 + d] / (nqs[c] * nks[d]) * tmp;
      row[d] = v;
      m = fmaxf(m, v);
    }
    float ssum = 0.f;
#pragma unroll
    for (int d = 0; d < 24; ++d) { float e = __expf(row[d] - m); row[d] = e; ssum += e; }
    const float inv = 1.f / ssum;
#pragma unroll
    for (int d = 0; d < 24; ++d) attn[c][d] = row[d] * inv;
  }
  __syncthreads();
  for (int e = tid; e < 192 * 24; e += 256) {
    int o = e / 24, d = e % 24;
    float a = 0.f;
#pragma unroll
    for (int c = 0; c < 24; ++c) a += projw[o * 192 + h * 24 + c] * attn[c][d];
    wcomb[o * 192 + h * 24 + d] = a;
  }
}

// ---------------------------------------------------------------------------
extern "C" void kernel_launch(void* const* d_in, const int* in_sizes, int n_in,
                              void* d_out, int out_size, void* d_ws, size_t ws_size,
                              hipStream_t stream) {
  const float* x      = (const float*)d_in[0];
  const float* qkv_w  = (const float*)d_in[1];
  const float* qkv_b  = (const float*)d_in[2];
  const float* dw_w   = (const float*)d_in[3];
  const float* dw_b   = (const float*)d_in[4];
  const float* temp   = (const float*)d_in[5];
  const float* proj_w = (const float*)d_in[6];
  const float* proj_b = (const float*)d_in[7];
  float* out = (float*)d_out;

  char* ws = (char*)d_ws;
  size_t off = 0;
  unsigned short* post = (unsigned short*)(ws + off);
  off += (size_t)C3 * NTOK * sizeof(unsigned short);           // 37.75 MB
  float* Sb0  = (float*)(ws + off);
  float* nqb0 = Sb0 + 2 * HEADS * HD * HD;
  float* nkb0 = nqb0 + 2 * HEADS * HD;
  size_t stotal = (size_t)(2 * HEADS * HD * HD + 4 * HEADS * HD) * sizeof(float);
  off += stotal;
  float* wcomb = (float*)(ws + off); off += (size_t)CIN * CIN * sizeof(float);
  off = (off + 255) & ~(size_t)255;
  unsigned short* atab = (unsigned short*)(ws + off);
  off += (size_t)C3 * 27 * 64 * 8 * sizeof(unsigned short);    // 15.9 MB
  off = (off + 255) & ~(size_t)255;
  unsigned short* pre = (unsigned short*)(ws + off);

  size_t remain = (ws_size > off) ? ws_size - off : 0;
  int CH = (int)(remain / ((size_t)NTOK * sizeof(unsigned short)));
  if (CH > C3) CH = C3;
  CH = (CH / 64) * 64;
  if (CH < 64) CH = 64;

  hipMemsetAsync(Sb0, 0, stotal, stream);
  k_build_atab<<<C3, 64, 0, stream>>>(dw_w, atab);

  for (int b = 0; b < 2; ++b) {
    const float* xb = x + (size_t)b * CIN * NTOK;
    for (int cs = 0; cs < C3; cs += CH) {
      int cc = C3 - cs; if (cc > CH) cc = CH;
      int ot = cc / 64;
      dim3 g1((NTOK / 64) * ot);
      k_gemm_mfma<0, 0><<<g1, 256, 0, stream>>>(xb, qkv_w + (size_t)cs * CIN,
                                                qkv_b + cs, pre, ot);
      dim3 g2(2, cc);
      k_dwconv_mfma<<<g2, 256, 0, stream>>>(pre, atab, dw_b, post, cs);
    }
    float* Sb  = Sb0 + (size_t)b * HEADS * HD * HD;
    float* nqb = nqb0 + (size_t)b * HEADS * HD;
    float* nkb = nkb0 + (size_t)b * HEADS * HD;
    dim3 g3(32, HEADS);
    k_gram<<<g3, 256, 0, stream>>>(post, Sb, nqb, nkb);
    k_attn_wcomb<<<HEADS, 256, 0, stream>>>(Sb, nqb, nkb, temp, proj_w, wcomb);
    dim3 g5((NTOK / 64) * 3);
    k_gemm_mfma<1, 1><<<g5, 256, 0, stream>>>(post + (size_t)384 * NTOK, wcomb,
                                              proj_b, out + (size_t)b * CIN * NTOK, 3);
  }
}

// Round 5
// 218.633 us; speedup vs baseline: 2.4032x; 2.4032x over previous
//
#include <hip/hip_runtime.h>

#define NTOK 32768   // 8*64*64 tokens
#define CIN 192
#define C3 576
#define HEADS 8
#define HD 24

typedef __attribute__((ext_vector_type(8))) short bf16x8;
typedef __attribute__((ext_vector_type(16))) float f32x16;
typedef __attribute__((ext_vector_type(4))) unsigned int u32x4;

__device__ __forceinline__ float bf2f(unsigned int u) {
  union { unsigned int i; float f; } x; x.i = u << 16; return x.f;
}
__device__ __forceinline__ unsigned short f2bf(float f) {
  union { float f; unsigned int i; } x; x.f = f;
  unsigned int r = x.i + 0x7fffu + ((x.i >> 16) & 1u);
  return (unsigned short)(r >> 16);
}

// ---------------------------------------------------------------------------
// MFMA GEMM: Y[o,n] = bias[o] + sum_{c<192} W[o,c] * X[c,n]
// block 256 = 4 waves; tile 64(o) x 64(n); full K=192 staged once.
// 1D grid, XCD-chunked swizzle (o fastest within an XCD's n-range).
// ---------------------------------------------------------------------------
template<int XBF, int OUTF32>
__global__ __launch_bounds__(256) void k_gemm_mfma(
    const void* __restrict__ Xv, const float* __restrict__ W,
    const float* __restrict__ bias, void* __restrict__ Yv, int ot)
{
  __shared__ __align__(16) unsigned short Wl[64][200];
  __shared__ __align__(16) unsigned short Xs[64][200];
  const int tid = threadIdx.x;
  const int bid = blockIdx.x;
  const int loc = bid >> 3;
  const int n0 = ((bid & 7) * 64 + loc / ot) * 64;
  const int o0 = (loc % ot) * 64;

  { // stage W (fp32 -> bf16)
    const int oo = tid >> 2;
    const int q0 = tid & 3;
#pragma unroll
    for (int j = 0; j < 12; ++j) {
      const int c = (j * 4 + q0) * 4;
      float4 v = *(const float4*)&W[(size_t)(o0 + oo) * CIN + c];
      Wl[oo][c]     = f2bf(v.x);
      Wl[oo][c + 1] = f2bf(v.y);
      Wl[oo][c + 2] = f2bf(v.z);
      Wl[oo][c + 3] = f2bf(v.w);
    }
  }
  { // stage X transposed -> Xs[n][c]; 4 n per thread, 16 c-groups
    const int nn = (tid & 15) * 4;
    const int cg = tid >> 4;           // 0..15
    if (XBF) {
      const unsigned short* X = (const unsigned short*)Xv;
#pragma unroll
      for (int j = 0; j < 12; ++j) {
        const int c = j * 16 + cg;
        unsigned short t4[4];
        *(unsigned long long*)t4 = *(const unsigned long long*)&X[(size_t)c * NTOK + n0 + nn];
        Xs[nn][c]     = t4[0];
        Xs[nn + 1][c] = t4[1];
        Xs[nn + 2][c] = t4[2];
        Xs[nn + 3][c] = t4[3];
      }
    } else {
      const float* X = (const float*)Xv;
#pragma unroll
      for (int j = 0; j < 12; ++j) {
        const int c = j * 16 + cg;
        float4 v = *(const float4*)&X[(size_t)c * NTOK + n0 + nn];
        Xs[nn][c]     = f2bf(v.x);
        Xs[nn + 1][c] = f2bf(v.y);
        Xs[nn + 2][c] = f2bf(v.z);
        Xs[nn + 3][c] = f2bf(v.w);
      }
    }
  }
  __syncthreads();

  const int lane = tid & 63;
  const int wv = tid >> 6;
  const int o_w = (wv >> 1) * 32;
  const int n_w = (wv & 1) * 32;
  const int r32 = lane & 31;
  const int hi = lane >> 5;

  f32x16 acc;
#pragma unroll
  for (int i = 0; i < 16; ++i) acc[i] = 0.f;

  const unsigned short* wp = &Wl[o_w + r32][hi * 8];
  const unsigned short* xp = &Xs[n_w + r32][hi * 8];
#pragma unroll
  for (int kk = 0; kk < 12; ++kk) {
    bf16x8 a = *(const bf16x8*)(wp + kk * 16);
    bf16x8 b = *(const bf16x8*)(xp + kk * 16);
    acc = __builtin_amdgcn_mfma_f32_32x32x16_bf16(a, b, acc, 0, 0, 0);
  }
  __syncthreads();

  if (OUTF32) {
    float (*Yl)[68] = (float(*)[68])&Wl[0][0];
#pragma unroll
    for (int r = 0; r < 16; ++r) {
      const int row = o_w + (r & 3) + 8 * (r >> 2) + 4 * hi;
      Yl[row][n_w + r32] = acc[r] + bias[o0 + row];
    }
    __syncthreads();
    float* Y = (float*)Yv;
    const int row = tid >> 2, seg = (tid & 3) * 16;
#pragma unroll
    for (int v = 0; v < 4; ++v) {
      float4 val = *(const float4*)&Yl[row][seg + v * 4];
      *(float4*)&Y[(size_t)(o0 + row) * NTOK + n0 + seg + v * 4] = val;
    }
  } else {
    unsigned short (*Yl)[72] = (unsigned short(*)[72])&Wl[0][0];
#pragma unroll
    for (int r = 0; r < 16; ++r) {
      const int row = o_w + (r & 3) + 8 * (r >> 2) + 4 * hi;
      Yl[row][n_w + r32] = f2bf(acc[r] + bias[o0 + row]);
    }
    __syncthreads();
    unsigned short* Y = (unsigned short*)Yv;
    const int row = tid >> 2, seg = (tid & 3) * 16;
#pragma unroll
    for (int v = 0; v < 2; ++v) {
      bf16x8 val = *(const bf16x8*)&Yl[row][seg + v * 8];
      *(bf16x8*)&Y[(size_t)(o0 + row) * NTOK + n0 + seg + v * 8] = val;
    }
  }
}

// ---------------------------------------------------------------------------
// K2: depthwise 3x3x3, pad 1, bf16 in/out, fp32 math.
// Register sliding-window; bf16 LDS (21.9 KB), 16B-aligned dwordx4 staging.
// s[t][r][col]: input w stored at col w+8 (cols 8..71); cols 7 & 72 zero halo.
// __launch_bounds__(256,4): 128-VGPR cap so acc[32]+v[18]+wr[27] stay resident.
// ---------------------------------------------------------------------------
__global__ __launch_bounds__(256, 4) void k_dwconv(
    const unsigned short* __restrict__ in,   // [CH_chunk][8][64][64] bf16
    const float* __restrict__ wdw,           // [576][27]
    const float* __restrict__ bdw,           // [576]
    unsigned short* __restrict__ out,        // [576][8][64][64] bf16
    int c_start)
{
  __shared__ __align__(16) unsigned short s[8][18][76];
  const int tid = threadIdx.x;
  const int chl = blockIdx.y;
  const int ch = c_start + chl;
  const int h0 = blockIdx.x * 16;
  const unsigned short* inch = in + (size_t)chl * NTOK;

  // zero halo cols
  for (int r = tid; r < 144; r += 256) {
    const int t = r / 18, rr = r % 18;
    s[t][rr][7] = 0;
    s[t][rr][72] = 0;
  }
  // stage rows: 144 rows x 8 segs of 8 shorts (16B aligned at col 8+seg*8)
  for (int idx = tid; idx < 144 * 8; idx += 256) {
    const int row = idx >> 3, seg = idx & 7;
    const int t = row / 18, rr = row % 18;
    const int h = h0 + rr - 1;
    u32x4 v = {0u, 0u, 0u, 0u};
    if (h >= 0 && h < 64)
      v = *(const u32x4*)&inch[t * 4096 + h * 64 + seg * 8];
    *(u32x4*)&s[t][rr][8 + seg * 8] = v;
  }
  float wr[27];
#pragma unroll
  for (int i = 0; i < 27; ++i) wr[i] = wdw[ch * 27 + i];
  const float bias = bdw[ch];
  __syncthreads();

  const int wloc = tid & 63;
  const int hl0 = (tid >> 6) * 4;
  float acc[8][4];
#pragma unroll
  for (int t = 0; t < 8; ++t)
#pragma unroll
    for (int i = 0; i < 4; ++i) acc[t][i] = 0.f;

#pragma unroll
  for (int tt = 0; tt < 8; ++tt) {
    float v[6][3];
#pragma unroll
    for (int r = 0; r < 6; ++r)
#pragma unroll
      for (int c = 0; c < 3; ++c)
        v[r][c] = bf2f(s[tt][hl0 + r][7 + wloc + c]);
#pragma unroll
    for (int p = 0; p < 3; ++p) {     // weight t-plane
      const int t = tt + 1 - p;       // output t receiving this plane
      if (t < 0 || t > 7) continue;   // compile-time pruned
#pragma unroll
      for (int hi = 0; hi < 4; ++hi) {
        float a = 0.f;
#pragma unroll
        for (int dh = 0; dh < 3; ++dh)
#pragma unroll
          for (int dw = 0; dw < 3; ++dw)
            a += wr[p * 9 + dh * 3 + dw] * v[hi + dh][dw];
        acc[t][hi] += a;
      }
    }
  }

  unsigned short* outch = out + (size_t)ch * NTOK;
#pragma unroll
  for (int t = 0; t < 8; ++t)
#pragma unroll
    for (int hi = 0; hi < 4; ++hi)
      outch[t * 4096 + (h0 + hl0 + hi) * 64 + wloc] = f2bf(acc[t][hi] + bias);
}

// ---------------------------------------------------------------------------
// K3: Gram via MFMA, fragments loaded DIRECTLY from global (no LDS staging).
// A lane layout (32x32x16): row i = lane&31, k = (lane>>5)*8+e -> contiguous
// bf16x8 at q[c=lane&31][n0+(lane>>5)*8]. B mirrors with k-rows. Rows 24..31
// read neighbor channels (in-bounds) and are masked out of the reduction.
// grid (32 n-blocks of 1024, 8 heads); LDS reduce then global atomics.
// ---------------------------------------------------------------------------
__global__ __launch_bounds__(256) void k_gram(
    const unsigned short* __restrict__ post,
    float* __restrict__ Sb, float* __restrict__ nqb, float* __restrict__ nkb)
{
  const int tid = threadIdx.x;
  const int h = blockIdx.y;
  const int lane = tid & 63;
  const int wv = tid >> 6;
  const int c = lane & 31;
  const int off = (lane >> 5) * 8;
  const unsigned short* q = post + (size_t)(h * HD + c) * NTOK;
  const unsigned short* k = post + (size_t)(192 + h * HD + c) * NTOK;

  __shared__ float Sl[24][25];
  __shared__ float nl[48];
  for (int i = tid; i < 600; i += 256) ((float*)Sl)[i] = 0.f;
  if (tid < 48) nl[tid] = 0.f;
  __syncthreads();

  f32x16 acc;
#pragma unroll
  for (int i = 0; i < 16; ++i) acc[i] = 0.f;
  float sqq = 0.f, sqk = 0.f;

  const int base = blockIdx.x * 1024 + wv * 256 + off;
#pragma unroll
  for (int i = 0; i < 16; ++i) {
    const int n = base + i * 16;
    bf16x8 a = *(const bf16x8*)&q[n];
    bf16x8 b = *(const bf16x8*)&k[n];
#pragma unroll
    for (int e = 0; e < 8; ++e) {
      float fa = bf2f((unsigned short)a[e]);
      float fb = bf2f((unsigned short)b[e]);
      sqq += fa * fa;
      sqk += fb * fb;
    }
    acc = __builtin_amdgcn_mfma_f32_32x32x16_bf16(a, b, acc, 0, 0, 0);
  }

  // norms: lanes l and l+32 share row c
  sqq += __shfl_down(sqq, 32, 64);
  sqk += __shfl_down(sqk, 32, 64);
  if (lane < 32 && c < 24) {
    atomicAdd(&nl[c], sqq);
    atomicAdd(&nl[24 + c], sqk);
  }
  // S[c_r][d]: d = lane&31, row from reg index
  if (c < 24) {
#pragma unroll
    for (int r = 0; r < 16; ++r) {
      const int row = (r & 3) + 8 * (r >> 2) + 4 * (lane >> 5);
      if (row < 24) atomicAdd(&Sl[row][c], acc[r]);
    }
  }
  __syncthreads();
  for (int i = tid; i < 576; i += 256)
    atomicAdd(&Sb[h * 576 + i], Sl[i / 24][i % 24]);
  if (tid < 24) atomicAdd(&nqb[h * 24 + tid], nl[tid]);
  else if (tid < 48) atomicAdd(&nkb[h * 24 + tid - 24], nl[tid]);
}

// ---------------------------------------------------------------------------
// K4: attn = softmax(S*temp/(|q||k|)); Wcomb = projW @ attn (per head)
// ---------------------------------------------------------------------------
__global__ __launch_bounds__(256) void k_attn_wcomb(
    const float* __restrict__ Sb, const float* __restrict__ nqb,
    const float* __restrict__ nkb, const float* __restrict__ temp,
    const float* __restrict__ projw, float* __restrict__ wcomb)
{
  const int h = blockIdx.x;
  const int tid = threadIdx.x;
  __shared__ float attn[24][25];
  __shared__ float nqs[24], nks[24];
  if (tid < 24) nqs[tid] = fmaxf(sqrtf(nqb[h * 24 + tid]), 1e-12f);
  else if (tid < 48) nks[tid - 24] = fmaxf(sqrtf(nkb[h * 24 + tid - 24]), 1e-12f);
  __syncthreads();
  if (tid < 24) {
    const int c = tid;
    const float tmp = temp[h];
    float row[24];
    float m = -1e30f;
#pragma unroll
    for (int d = 0; d < 24; ++d) {
      float v = Sb[h * 576 + c * 24 + d] / (nqs[c] * nks[d]) * tmp;
      row[d] = v;
      m = fmaxf(m, v);
    }
    float ssum = 0.f;
#pragma unroll
    for (int d = 0; d < 24; ++d) { float e = __expf(row[d] - m); row[d] = e; ssum += e; }
    const float inv = 1.f / ssum;
#pragma unroll
    for (int d = 0; d < 24; ++d) attn[c][d] = row[d] * inv;
  }
  __syncthreads();
  for (int e = tid; e < 192 * 24; e += 256) {
    int o = e / 24, d = e % 24;
    float a = 0.f;
#pragma unroll
    for (int c = 0; c < 24; ++c) a += projw[o * 192 + h * 24 + c] * attn[c][d];
    wcomb[o * 192 + h * 24 + d] = a;
  }
}

// ---------------------------------------------------------------------------
extern "C" void kernel_launch(void* const* d_in, const int* in_sizes, int n_in,
                              void* d_out, int out_size, void* d_ws, size_t ws_size,
                              hipStream_t stream) {
  const float* x      = (const float*)d_in[0];
  const float* qkv_w  = (const float*)d_in[1];
  const float* qkv_b  = (const float*)d_in[2];
  const float* dw_w   = (const float*)d_in[3];
  const float* dw_b   = (const float*)d_in[4];
  const float* temp   = (const float*)d_in[5];
  const float* proj_w = (const float*)d_in[6];
  const float* proj_b = (const float*)d_in[7];
  float* out = (float*)d_out;

  char* ws = (char*)d_ws;
  size_t off = 0;
  unsigned short* post = (unsigned short*)(ws + off);
  off += (size_t)C3 * NTOK * sizeof(unsigned short);           // 37.75 MB
  float* Sb0  = (float*)(ws + off);
  float* nqb0 = Sb0 + 2 * HEADS * HD * HD;
  float* nkb0 = nqb0 + 2 * HEADS * HD;
  size_t stotal = (size_t)(2 * HEADS * HD * HD + 4 * HEADS * HD) * sizeof(float);
  off += stotal;
  float* wcomb = (float*)(ws + off); off += (size_t)CIN * CIN * sizeof(float);
  off = (off + 255) & ~(size_t)255;
  unsigned short* pre = (unsigned short*)(ws + off);

  size_t remain = (ws_size > off) ? ws_size - off : 0;
  int CH = (int)(remain / ((size_t)NTOK * sizeof(unsigned short)));
  if (CH > C3) CH = C3;
  CH = (CH / 64) * 64;
  if (CH < 64) CH = 64;

  hipMemsetAsync(Sb0, 0, stotal, stream);

  for (int b = 0; b < 2; ++b) {
    const float* xb = x + (size_t)b * CIN * NTOK;
    for (int cs = 0; cs < C3; cs += CH) {
      int cc = C3 - cs; if (cc > CH) cc = CH;
      int ot = cc / 64;
      dim3 g1((NTOK / 64) * ot);
      k_gemm_mfma<0, 0><<<g1, 256, 0, stream>>>(xb, qkv_w + (size_t)cs * CIN,
                                                qkv_b + cs, pre, ot);
      dim3 g2(4, cc);
      k_dwconv<<<g2, 256, 0, stream>>>(pre, dw_w, dw_b, post, cs);
    }
    float* Sb  = Sb0 + (size_t)b * HEADS * HD * HD;
    float* nqb = nqb0 + (size_t)b * HEADS * HD;
    float* nkb = nkb0 + (size_t)b * HEADS * HD;
    dim3 g3(32, HEADS);
    k_gram<<<g3, 256, 0, stream>>>(post, Sb, nqb, nkb);
    k_attn_wcomb<<<HEADS, 256, 0, stream>>>(Sb, nqb, nkb, temp, proj_w, wcomb);
    dim3 g5((NTOK / 64) * 3);
    k_gemm_mfma<1, 1><<<g5, 256, 0, stream>>>(post + (size_t)384 * NTOK, wcomb,
                                              proj_b, out + (size_t)b * CIN * NTOK, 3);
  }
}